// Round 7
// baseline (187.176 us; speedup 1.0000x reference)
//
#include <hip/hip_runtime.h>
#include <math.h>

static constexpr int kM = 80;
static constexpr int kT = 4000;
static constexpr int kB = 64;
static constexpr int kLow = kM / 3;                 // 26
static constexpr int kHighStart = 2 * kM / 3;       // 53
static constexpr int kHighCount = kM - kHighStart;  // 27
static constexpr int kC = 512;     // emit columns per block
static constexpr int kW = 256;     // warmup columns (err <= 0.95^256 ~ 2e-6)
static constexpr int kE = 12;      // elems per lane: 64*12 = 768 = kW + kC
static constexpr int kChunks = 8;  // 8*512 = 4096 >= 4000
#define EPSF 1e-6f
#define LOG2E 1.4426950408889634f

typedef float vfloat4 __attribute__((ext_vector_type(4)));
typedef float vfloat2 __attribute__((ext_vector_type(2)));

// HW transcendentals: v_exp_f32 computes 2^x, v_log_f32 computes log2(x)
__device__ __forceinline__ float hw_exp2(float x) { return __builtin_amdgcn_exp2f(x); }
__device__ __forceinline__ float hw_log2(float x) { return __builtin_amdgcn_logf(x); }

__device__ __forceinline__ float fast_sigmoid(float x) {
    return __builtin_amdgcn_rcpf(1.0f + hw_exp2(-x * LOG2E));
}

// Fused gate + dual-PCEN kernel.
// Block = 512 thr (8 waves), grid (8 t-chunks, 64 b) = 512 blocks.
// Phase 0: threads 0..79 stage per-channel params into LDS.
// Phase 1: thread tid computes gate for column c0+tid (owns the full
//          80-channel reduction -> no cross-thread reduce), gate -> LDS.
// Phase 2: each wave processes 10 rows; per row a wave-local chunked affine
//          scan over the 768-col window [ws, ws+768) = [c0-256, c0+512)
//          (block 0: [0,768), exact carry sm[-1]=x[0]); emit [c0, c0+512).
__global__ __launch_bounds__(512) void fused_kernel(
    const float* __restrict__ mel,
    const float* __restrict__ ls_ns, const float* __restrict__ la_ns,
    const float* __restrict__ ld_ns, const float* __restrict__ lr_ns,
    const float* __restrict__ ls_st, const float* __restrict__ la_st,
    const float* __restrict__ ld_st, const float* __restrict__ lr_st,
    const float* __restrict__ gate_temp,
    float* __restrict__ out)
{
    const int j   = blockIdx.x;          // t-chunk
    const int b   = blockIdx.y;
    const int c0  = j * kC;
    const int tid = threadIdx.x;
    const int lane = tid & 63;
    const int wid  = tid >> 6;

    __shared__ float gate_s[kC];         // 2 KB
    __shared__ vfloat4 prm[kM][3];       // 3.75 KB: per-channel derived params

    // ---------- phase 0: per-channel params ----------
    if (tid < kM) {
        const int m = tid;
        const float s_ns     = fminf(fmaxf(fast_sigmoid(ls_ns[m]), 0.05f), 0.3f);
        const float alpha_ns = fminf(fmaxf(fast_sigmoid(la_ns[m]), 0.9f), 0.999f);
        const float delta_ns = fminf(fmaxf(hw_exp2(ld_ns[m] * LOG2E), 0.5f), 5.0f);
        const float r_ns     = fminf(fmaxf(fast_sigmoid(lr_ns[m]), 0.05f), 0.25f);
        const float s_st     = fminf(fmaxf(fast_sigmoid(ls_st[m]), 0.05f), 0.3f);
        const float alpha_st = fminf(fmaxf(fast_sigmoid(la_st[m]), 0.9f), 0.999f);
        const float delta_st = fminf(fmaxf(hw_exp2(ld_st[m] * LOG2E), 0.001f), 0.1f);
        const float r_st     = fminf(fmaxf(fast_sigmoid(lr_st[m]), 0.05f), 0.25f);
        vfloat4 w0; w0.x = 1.0f - s_ns; w0.y = 1.0f - s_st; w0.z = s_ns; w0.w = s_st;
        vfloat4 w1; w1.x = delta_ns; w1.y = delta_st; w1.z = -alpha_ns; w1.w = -alpha_st;
        vfloat4 w2; w2.x = r_ns; w2.y = r_st;
        w2.z = hw_exp2(r_ns * hw_log2(delta_ns));   // delta^r
        w2.w = hw_exp2(r_st * hw_log2(delta_st));
        prm[m][0] = w0; prm[m][1] = w1; prm[m][2] = w2;
    }

    // ---------- phase 1: gate for columns [c0, c0+kC) ----------
    {
        const int col = c0 + tid;        // tid < 512 == kC
        if (col < kT) {
            const float* base = mel + (size_t)b * kM * kT + col;
            float slog = 0.f, ssum = 0.f, slow = 0.f, shigh = 0.f;
            #pragma unroll
            for (int m = 0; m < kM; ++m) {         // branches fold at unroll
                const float v = base[(size_t)m * kT];
                slog += hw_log2(v + 1e-8f);
                ssum += v;
                if (m < kLow)        slow  += v;
                if (m >= kHighStart) shigh += v;
            }
            const float geo   = hw_exp2(slog * (1.0f / kM));
            const float arith = ssum * (1.0f / kM) + 1e-8f;
            float sf = geo * __builtin_amdgcn_rcpf(arith);
            sf = fminf(fmaxf(sf, 0.0f), 1.0f);
            const float low  = slow  * (1.0f / kLow);
            const float high = shigh * (1.0f / kHighCount);
            float tilt = low * __builtin_amdgcn_rcpf(low + high + 1e-8f);
            tilt = fminf(fmaxf(tilt, 0.0f), 1.0f);
            const float sfa = sf + (1.0f - sf) * fmaxf(tilt - 0.6f, 0.0f);
            gate_s[tid] = fast_sigmoid(gate_temp[0] * (sfa - 0.5f));
        }
    }
    __syncthreads();

    // ---------- phase 2: dual PCEN scan, 10 rows per wave ----------
    const int ws = (j == 0) ? 0 : (c0 - kW);       // window start
    const int base_col = ws + lane * kE;
    const bool xvalid = (base_col + kE <= kT);     // whole-lane (4000-3328=12*56)

    for (int i = 0; i < 10; ++i) {
        const int m = wid * 10 + i;
        const vfloat4 w0 = prm[m][0];
        const vfloat4 w1 = prm[m][1];
        const vfloat4 w2 = prm[m][2];
        const vfloat2 a2 = {w0.x, w0.y};
        const vfloat2 s2 = {w0.z, w0.w};
        const vfloat2 d2 = {w1.x, w1.y};
        const float man = w1.z, mas = w1.w;
        const float r_ns = w2.x, r_st = w2.y, dr_ns = w2.z, dr_st = w2.w;
        const size_t rowoff = (size_t)(b * kM + m) * kT;

        float x[kE];
        if (xvalid) {
            const vfloat4* rp = reinterpret_cast<const vfloat4*>(mel + rowoff + base_col);
            #pragma unroll
            for (int q = 0; q < 3; ++q) {
                const vfloat4 v = rp[q];
                x[4*q+0] = v.x; x[4*q+1] = v.y; x[4*q+2] = v.z; x[4*q+3] = v.w;
            }
        } else {
            #pragma unroll
            for (int k = 0; k < kE; ++k) x[k] = 0.0f;
        }

        // local affine transform over kE elems: v -> A*v + B ; A = a^12
        vfloat2 Bv = {0.0f, 0.0f};
        #pragma unroll
        for (int k = 0; k < kE; ++k) Bv = a2 * Bv + s2 * x[k];
        const vfloat2 p2 = a2 * a2;
        const vfloat2 p4 = p2 * p2;
        const vfloat2 p8 = p4 * p4;
        vfloat2 Av = p8 * p4;                      // a^12

        // inclusive Hillis-Steele composition scan across the wave
        #pragma unroll
        for (int d = 1; d < 64; d <<= 1) {
            const float qAn = __shfl_up(Av.x, d);
            const float qAs = __shfl_up(Av.y, d);
            const float qBn = __shfl_up(Bv.x, d);
            const float qBs = __shfl_up(Bv.y, d);
            if (lane >= d) {
                const vfloat2 qA = {qAn, qAs};
                const vfloat2 qB = {qBn, qBs};
                Bv = Av * qB + Bv;
                Av = Av * qA;
            }
        }

        // exclusive prefix + carry v0 = x[window start] (exact for j==0)
        vfloat2 eA, eB;
        eA.x = __shfl_up(Av.x, 1); eA.y = __shfl_up(Av.y, 1);
        eB.x = __shfl_up(Bv.x, 1); eB.y = __shfl_up(Bv.y, 1);
        if (lane == 0) { eA = (vfloat2){1.0f, 1.0f}; eB = (vfloat2){0.0f, 0.0f}; }
        const float x0 = __shfl(x[0], 0);
        const vfloat2 v0 = {x0, x0};
        vfloat2 sm = eA * v0 + eB;

        // replay in quads (kW and kT are multiples of 4 -> quads never split)
        #pragma unroll
        for (int q = 0; q < 3; ++q) {
            const int colq = base_col + 4 * q;
            const bool emit = (colq >= c0) && (colq < c0 + kC) && (colq < kT);
            vfloat4 g4 = {0.f, 0.f, 0.f, 0.f};
            if (emit) g4 = *reinterpret_cast<const vfloat4*>(gate_s + (colq - c0));
            vfloat4 r4;
            #pragma unroll
            for (int kk = 0; kk < 4; ++kk) {
                const float xv = x[4*q+kk];
                sm = a2 * sm + s2 * xv;            // v_pk_fma_f32
                if (emit) {
                    vfloat2 g2;
                    g2.x = hw_exp2(man * hw_log2(sm.x + EPSF));
                    g2.y = hw_exp2(mas * hw_log2(sm.y + EPSF));
                    const vfloat2 u2 = g2 * xv + d2;
                    const float on = hw_exp2(r_ns * hw_log2(u2.x)) - dr_ns;
                    const float os = hw_exp2(r_st * hw_log2(u2.y)) - dr_st;
                    r4[kk] = fmaf(g4[kk], os - on, on);
                }
            }
            if (emit) {
                *reinterpret_cast<vfloat4*>(out + rowoff + colq) = r4;
            }
        }
    }
}

extern "C" void kernel_launch(void* const* d_in, const int* in_sizes, int n_in,
                              void* d_out, int out_size, void* d_ws, size_t ws_size,
                              hipStream_t stream)
{
    const float* mel       = (const float*)d_in[0];
    const float* ls_ns     = (const float*)d_in[1];
    const float* la_ns     = (const float*)d_in[2];
    const float* ld_ns     = (const float*)d_in[3];
    const float* lr_ns     = (const float*)d_in[4];
    const float* ls_st     = (const float*)d_in[5];
    const float* la_st     = (const float*)d_in[6];
    const float* ld_st     = (const float*)d_in[7];
    const float* lr_st     = (const float*)d_in[8];
    const float* gate_temp = (const float*)d_in[9];
    float* out  = (float*)d_out;

    dim3 g(kChunks, kB);                 // 512 blocks x 512 threads
    fused_kernel<<<g, 512, 0, stream>>>(mel, ls_ns, la_ns, ld_ns, lr_ns,
                                        ls_st, la_st, ld_st, lr_st,
                                        gate_temp, out);
}